// Round 1
// baseline (2988.557 us; speedup 1.0000x reference)
//
#include <hip/hip_runtime.h>

#define IN_DIM 128
#define HID 64
#define NEG 0.01f

// K1: p = h @ W   (M x 128) @ (128 x 64), f32
__global__ __launch_bounds__(256) void gemm_h_w(const float* __restrict__ h,
                                                const float* __restrict__ W,
                                                float* __restrict__ p, int M) {
    __shared__ float Ws[IN_DIM * HID];   // 32 KB
    __shared__ float hs[4][IN_DIM];      // 2 KB
    int tid = threadIdx.x;
    for (int i = tid; i < IN_DIM * HID; i += 256) Ws[i] = W[i];
    int row0 = blockIdx.x * 4;
    for (int i = tid; i < 4 * IN_DIM; i += 256) {
        int r = i >> 7, k = i & 127;
        int row = row0 + r;
        hs[r][k] = (row < M) ? h[(long long)row * IN_DIM + k] : 0.f;
    }
    __syncthreads();
    int r = tid >> 6, c = tid & 63;
    int row = row0 + r;
    if (row >= M) return;
    float acc = 0.f;
#pragma unroll
    for (int k = 0; k < IN_DIM; ++k)
        acc = fmaf(hs[r][k], Ws[k * HID + c], acc);
    p[(long long)row * HID + c] = acc;
}

// K2: agg[dst[e]] += p[src[e]]  (64 floats per edge, float4 gather, 4 atomics/thread)
__global__ __launch_bounds__(256) void agg_edges(const float* __restrict__ p,
                                                 const int* __restrict__ src,
                                                 const int* __restrict__ dst,
                                                 float* __restrict__ agg, int nE) {
    int i = blockIdx.x * 256 + threadIdx.x;   // nE*16 = 25.6M fits int
    int total = nE * 16;
    if (i >= total) return;
    int e = i >> 4, q = i & 15;
    int s = src[e], d = dst[e];
    float4 v = reinterpret_cast<const float4*>(p + (long long)s * HID)[q];
    float* a = agg + (long long)d * HID + q * 4;
    atomicAdd(a + 0, v.x);
    atomicAdd(a + 1, v.y);
    atomicAdd(a + 2, v.z);
    atomicAdd(a + 3, v.w);
}

// K3: t = relu(p1+agg1+b1a); h1 = leaky(t@W1b + b1b); p2 = h1@W2a  -> write p2
__global__ __launch_bounds__(256) void mlp_mid(const float* __restrict__ p1,
                                               const float* __restrict__ agg1,
                                               const float* __restrict__ b1a,
                                               const float* __restrict__ W1b,
                                               const float* __restrict__ b1b,
                                               const float* __restrict__ W2a,
                                               float* __restrict__ p2, int M) {
    __shared__ float Wb[HID * HID];   // 16 KB
    __shared__ float Wa2[HID * HID];  // 16 KB
    __shared__ float ts[4][HID];
    __shared__ float hs[4][HID];
    int tid = threadIdx.x;
    for (int i = tid; i < HID * HID; i += 256) { Wb[i] = W1b[i]; Wa2[i] = W2a[i]; }
    int r = tid >> 6, c = tid & 63;
    int row = blockIdx.x * 4 + r;
    float t = 0.f;
    if (row < M) {
        long long idx = (long long)row * HID + c;
        t = p1[idx] + agg1[idx] + b1a[c];
        t = fmaxf(t, 0.f);
    }
    ts[r][c] = t;
    __syncthreads();
    float acc = b1b[c];
#pragma unroll
    for (int k = 0; k < HID; ++k) acc = fmaf(ts[r][k], Wb[k * HID + c], acc);
    float h1 = (acc > 0.f) ? acc : acc * NEG;
    hs[r][c] = h1;
    __syncthreads();
    float acc2 = 0.f;
#pragma unroll
    for (int k = 0; k < HID; ++k) acc2 = fmaf(hs[r][k], Wa2[k * HID + c], acc2);
    if (row < M) p2[(long long)row * HID + c] = acc2;
}

// K6: t = relu(p2+agg2+b2a); out = leaky(t@W2b + b2b)
__global__ __launch_bounds__(256) void mlp_out(const float* __restrict__ p2,
                                               const float* __restrict__ agg2,
                                               const float* __restrict__ b2a,
                                               const float* __restrict__ W2b,
                                               const float* __restrict__ b2b,
                                               float* __restrict__ out, int M) {
    __shared__ float Wb[HID * HID];  // 16 KB
    __shared__ float ts[4][HID];
    int tid = threadIdx.x;
    for (int i = tid; i < HID * HID; i += 256) Wb[i] = W2b[i];
    int r = tid >> 6, c = tid & 63;
    int row = blockIdx.x * 4 + r;
    float t = 0.f;
    if (row < M) {
        long long idx = (long long)row * HID + c;
        t = p2[idx] + agg2[idx] + b2a[c];
        t = fmaxf(t, 0.f);
    }
    ts[r][c] = t;
    __syncthreads();
    float acc = b2b[c];
#pragma unroll
    for (int k = 0; k < HID; ++k) acc = fmaf(ts[r][k], Wb[k * HID + c], acc);
    float o = (acc > 0.f) ? acc : acc * NEG;
    if (row < M) out[(long long)row * HID + c] = o;
}

extern "C" void kernel_launch(void* const* d_in, const int* in_sizes, int n_in,
                              void* d_out, int out_size, void* d_ws, size_t ws_size,
                              hipStream_t stream) {
    const float* h   = (const float*)d_in[0];
    const int*   ei  = (const int*)d_in[1];
    const float* W1a = (const float*)d_in[2];
    const float* b1a = (const float*)d_in[3];
    const float* W1b = (const float*)d_in[4];
    const float* b1b = (const float*)d_in[5];
    const float* W2a = (const float*)d_in[6];
    const float* b2a = (const float*)d_in[7];
    const float* W2b = (const float*)d_in[8];
    const float* b2b = (const float*)d_in[9];

    int M  = in_sizes[0] / IN_DIM;  // 100000
    int nE = in_sizes[1] / 2;       // 1600000
    const int* src = ei;
    const int* dst = ei + nE;

    size_t matBytes = (size_t)M * HID * sizeof(float);  // 25.6 MB
    float* p1  = (float*)d_ws;
    float* agg = (float*)((char*)d_ws + matBytes);
    float* p2  = (float*)d_out;  // p2 lives in d_out; final kernel overwrites in place

    int mBlocks = (M + 3) / 4;
    int aBlocks = (nE * 16 + 255) / 256;

    // Layer 1
    hipMemsetAsync(agg, 0, matBytes, stream);
    gemm_h_w<<<mBlocks, 256, 0, stream>>>(h, W1a, p1, M);
    agg_edges<<<aBlocks, 256, 0, stream>>>(p1, src, dst, agg, nE);
    mlp_mid<<<mBlocks, 256, 0, stream>>>(p1, agg, b1a, W1b, b1b, W2a, p2, M);

    // Layer 2
    hipMemsetAsync(agg, 0, matBytes, stream);
    agg_edges<<<aBlocks, 256, 0, stream>>>(p2, src, dst, agg, nE);
    mlp_out<<<mBlocks, 256, 0, stream>>>(p2, agg, b2a, W2b, b2b, (float*)d_out, M);
}

// Round 2
// 575.974 us; speedup vs baseline: 5.1887x; 5.1887x over previous
//
#include <hip/hip_runtime.h>

#define IN_DIM 128
#define HID 64
#define NEG 0.01f
#define SCAN_CHUNK 1024   // elements per scan1 block (256 threads x 4)

// ---------- CSR build ----------

__global__ __launch_bounds__(256) void zero_i32(int* __restrict__ x, int n) {
    int i = blockIdx.x * 256 + threadIdx.x;
    if (i < n) x[i] = 0;
}

__global__ __launch_bounds__(256) void hist_dst(const int* __restrict__ dst,
                                                int* __restrict__ cnt, int nE) {
    int e = blockIdx.x * 256 + threadIdx.x;
    if (e < nE) atomicAdd(&cnt[dst[e]], 1);
}

// per-block local exclusive scan of cnt -> rp ; per-block totals -> bsum
__global__ __launch_bounds__(256) void scan1(const int* __restrict__ cnt,
                                             int* __restrict__ rp,
                                             int* __restrict__ bsum, int N) {
    __shared__ int sums[256];
    int t = threadIdx.x;
    int base = blockIdx.x * SCAN_CHUNK + t * 4;
    int v0 = (base + 0 < N) ? cnt[base + 0] : 0;
    int v1 = (base + 1 < N) ? cnt[base + 1] : 0;
    int v2 = (base + 2 < N) ? cnt[base + 2] : 0;
    int v3 = (base + 3 < N) ? cnt[base + 3] : 0;
    sums[t] = v0 + v1 + v2 + v3;
    __syncthreads();
    for (int off = 1; off < 256; off <<= 1) {
        int x = sums[t];
        int y = (t >= off) ? sums[t - off] : 0;
        __syncthreads();
        sums[t] = x + y;
        __syncthreads();
    }
    int excl = (t > 0) ? sums[t - 1] : 0;
    if (base + 0 < N) rp[base + 0] = excl;  excl += v0;
    if (base + 1 < N) rp[base + 1] = excl;  excl += v1;
    if (base + 2 < N) rp[base + 2] = excl;  excl += v2;
    if (base + 3 < N) rp[base + 3] = excl;
    if (t == 255) bsum[blockIdx.x] = sums[255];
}

// exclusive scan of block sums (B <= 128), single block of 128 threads
__global__ __launch_bounds__(128) void scan2(int* __restrict__ bsum, int B) {
    __shared__ int s[128];
    int t = threadIdx.x;
    s[t] = (t < B) ? bsum[t] : 0;
    __syncthreads();
    for (int off = 1; off < 128; off <<= 1) {
        int x = s[t];
        int y = (t >= off) ? s[t - off] : 0;
        __syncthreads();
        s[t] = x + y;
        __syncthreads();
    }
    if (t < B) bsum[t] = (t > 0) ? s[t - 1] : 0;
}

// add block offsets in place, mirror into cursor, set rp[N] = nE
__global__ __launch_bounds__(256) void scan3(int* __restrict__ rp,
                                             int* __restrict__ cursor,
                                             const int* __restrict__ bsum,
                                             int N, int nE) {
    int i = blockIdx.x * 256 + threadIdx.x;
    if (i < N) {
        int v = rp[i] + bsum[i >> 10];   // SCAN_CHUNK = 1024
        rp[i] = v;
        cursor[i] = v;
    }
    if (i == 0) rp[N] = nE;
}

__global__ __launch_bounds__(256) void scatter_edges(const int* __restrict__ src,
                                                     const int* __restrict__ dst,
                                                     int* __restrict__ cursor,
                                                     int* __restrict__ ssrc, int nE) {
    int e = blockIdx.x * 256 + threadIdx.x;
    if (e < nE) {
        int pos = atomicAdd(&cursor[dst[e]], 1);
        ssrc[pos] = src[e];
    }
}

// ---------- aggregation: one wave per node, lane = channel, no atomics ----------
__global__ __launch_bounds__(256) void agg_csr(const float* __restrict__ p,
                                               const int* __restrict__ rp,
                                               const int* __restrict__ ssrc,
                                               float* __restrict__ agg, int M) {
    int w = (blockIdx.x * 256 + threadIdx.x) >> 6;   // node id
    int lane = threadIdx.x & 63;
    if (w >= M) return;
    int beg = rp[w], end = rp[w + 1];
    float acc = 0.f;
    int i = beg;
    for (; i + 4 <= end; i += 4) {
        int s0 = ssrc[i], s1 = ssrc[i + 1], s2 = ssrc[i + 2], s3 = ssrc[i + 3];
        float a0 = p[(size_t)s0 * HID + lane];
        float a1 = p[(size_t)s1 * HID + lane];
        float a2 = p[(size_t)s2 * HID + lane];
        float a3 = p[(size_t)s3 * HID + lane];
        acc += a0 + a1 + a2 + a3;
    }
    for (; i < end; ++i) acc += p[(size_t)ssrc[i] * HID + lane];
    agg[(size_t)w * HID + lane] = acc;
}

// ---------- dense kernels (unchanged from round 1) ----------

__global__ __launch_bounds__(256) void gemm_h_w(const float* __restrict__ h,
                                                const float* __restrict__ W,
                                                float* __restrict__ p, int M) {
    __shared__ float Ws[IN_DIM * HID];
    __shared__ float hs[4][IN_DIM];
    int tid = threadIdx.x;
    for (int i = tid; i < IN_DIM * HID; i += 256) Ws[i] = W[i];
    int row0 = blockIdx.x * 4;
    for (int i = tid; i < 4 * IN_DIM; i += 256) {
        int r = i >> 7, k = i & 127;
        int row = row0 + r;
        hs[r][k] = (row < M) ? h[(long long)row * IN_DIM + k] : 0.f;
    }
    __syncthreads();
    int r = tid >> 6, c = tid & 63;
    int row = row0 + r;
    if (row >= M) return;
    float acc = 0.f;
#pragma unroll
    for (int k = 0; k < IN_DIM; ++k)
        acc = fmaf(hs[r][k], Ws[k * HID + c], acc);
    p[(long long)row * HID + c] = acc;
}

__global__ __launch_bounds__(256) void mlp_mid(const float* __restrict__ p1,
                                               const float* __restrict__ agg1,
                                               const float* __restrict__ b1a,
                                               const float* __restrict__ W1b,
                                               const float* __restrict__ b1b,
                                               const float* __restrict__ W2a,
                                               float* __restrict__ p2, int M) {
    __shared__ float Wb[HID * HID];
    __shared__ float Wa2[HID * HID];
    __shared__ float ts[4][HID];
    __shared__ float hs[4][HID];
    int tid = threadIdx.x;
    for (int i = tid; i < HID * HID; i += 256) { Wb[i] = W1b[i]; Wa2[i] = W2a[i]; }
    int r = tid >> 6, c = tid & 63;
    int row = blockIdx.x * 4 + r;
    float t = 0.f;
    if (row < M) {
        long long idx = (long long)row * HID + c;
        t = p1[idx] + agg1[idx] + b1a[c];
        t = fmaxf(t, 0.f);
    }
    ts[r][c] = t;
    __syncthreads();
    float acc = b1b[c];
#pragma unroll
    for (int k = 0; k < HID; ++k) acc = fmaf(ts[r][k], Wb[k * HID + c], acc);
    float h1 = (acc > 0.f) ? acc : acc * NEG;
    hs[r][c] = h1;
    __syncthreads();
    float acc2 = 0.f;
#pragma unroll
    for (int k = 0; k < HID; ++k) acc2 = fmaf(hs[r][k], Wa2[k * HID + c], acc2);
    if (row < M) p2[(long long)row * HID + c] = acc2;
}

__global__ __launch_bounds__(256) void mlp_out(const float* __restrict__ p2,
                                               const float* __restrict__ agg2,
                                               const float* __restrict__ b2a,
                                               const float* __restrict__ W2b,
                                               const float* __restrict__ b2b,
                                               float* __restrict__ out, int M) {
    __shared__ float Wb[HID * HID];
    __shared__ float ts[4][HID];
    int tid = threadIdx.x;
    for (int i = tid; i < HID * HID; i += 256) Wb[i] = W2b[i];
    int r = tid >> 6, c = tid & 63;
    int row = blockIdx.x * 4 + r;
    float t = 0.f;
    if (row < M) {
        long long idx = (long long)row * HID + c;
        t = p2[idx] + agg2[idx] + b2a[c];
        t = fmaxf(t, 0.f);
    }
    ts[r][c] = t;
    __syncthreads();
    float acc = b2b[c];
#pragma unroll
    for (int k = 0; k < HID; ++k) acc = fmaf(ts[r][k], Wb[k * HID + c], acc);
    float o = (acc > 0.f) ? acc : acc * NEG;
    if (row < M) out[(long long)row * HID + c] = o;
}

extern "C" void kernel_launch(void* const* d_in, const int* in_sizes, int n_in,
                              void* d_out, int out_size, void* d_ws, size_t ws_size,
                              hipStream_t stream) {
    const float* h   = (const float*)d_in[0];
    const int*   ei  = (const int*)d_in[1];
    const float* W1a = (const float*)d_in[2];
    const float* b1a = (const float*)d_in[3];
    const float* W1b = (const float*)d_in[4];
    const float* b1b = (const float*)d_in[5];
    const float* W2a = (const float*)d_in[6];
    const float* b2a = (const float*)d_in[7];
    const float* W2b = (const float*)d_in[8];
    const float* b2b = (const float*)d_in[9];

    int M  = in_sizes[0] / IN_DIM;  // 100000
    int nE = in_sizes[1] / 2;       // 1600000
    const int* src = ei;
    const int* dst = ei + nE;

    // workspace layout
    float* p1     = (float*)d_ws;                       // M*64 f32 (25.6 MB)
    float* agg    = p1 + (size_t)M * HID;               // M*64 f32 (25.6 MB)
    int*   rp     = (int*)(agg + (size_t)M * HID);      // M+1 ints
    int*   cursor = rp + (M + 1);                       // M ints
    int*   bsum   = cursor + M;                         // <=128 ints
    int*   ssrc   = bsum + 128;                         // nE ints (6.4 MB)

    float* p2 = (float*)d_out;   // layer-1 output lives in d_out

    int mBlocks   = (M + 3) / 4;
    int nB        = (M + 255) / 256;
    int eB        = (nE + 255) / 256;
    int scanB     = (M + SCAN_CHUNK - 1) / SCAN_CHUNK;  // 98 <= 128
    int aggBlocks = ((size_t)M * 64 + 255) / 256;

    // layer-1 projection (independent of CSR build)
    gemm_h_w<<<mBlocks, 256, 0, stream>>>(h, W1a, p1, M);

    // CSR build (reused by both layers)
    zero_i32<<<nB, 256, 0, stream>>>(cursor, M);
    hist_dst<<<eB, 256, 0, stream>>>(dst, cursor, nE);
    scan1<<<scanB, 256, 0, stream>>>(cursor, rp, bsum, M);
    scan2<<<1, 128, 0, stream>>>(bsum, scanB);
    scan3<<<nB, 256, 0, stream>>>(rp, cursor, bsum, M, nE);
    scatter_edges<<<eB, 256, 0, stream>>>(src, dst, cursor, ssrc, nE);

    // layer 1
    agg_csr<<<aggBlocks, 256, 0, stream>>>(p1, rp, ssrc, agg, M);
    mlp_mid<<<mBlocks, 256, 0, stream>>>(p1, agg, b1a, W1b, b1b, W2a, p2, M);

    // layer 2
    agg_csr<<<aggBlocks, 256, 0, stream>>>(p2, rp, ssrc, agg, M);
    mlp_out<<<mBlocks, 256, 0, stream>>>(p2, agg, b2a, W2b, b2b, (float*)d_out, M);
}

// Round 3
// 507.814 us; speedup vs baseline: 5.8851x; 1.1342x over previous
//
#include <hip/hip_runtime.h>

#define IN_DIM 128
#define HID 64
#define NEG 0.01f
#define SCAN_CHUNK 1024

__device__ __forceinline__ float rl(float v, int k) {
    return __int_as_float(__builtin_amdgcn_readlane(__float_as_int(v), k));
}

// ---------- CSR build (unchanged, proven) ----------

__global__ __launch_bounds__(256) void zero_i32(int* __restrict__ x, int n) {
    int i = blockIdx.x * 256 + threadIdx.x;
    if (i < n) x[i] = 0;
}

__global__ __launch_bounds__(256) void hist_dst(const int* __restrict__ dst,
                                                int* __restrict__ cnt, int nE) {
    int e = blockIdx.x * 256 + threadIdx.x;
    if (e < nE) atomicAdd(&cnt[dst[e]], 1);
}

__global__ __launch_bounds__(256) void scan1(const int* __restrict__ cnt,
                                             int* __restrict__ rp,
                                             int* __restrict__ bsum, int N) {
    __shared__ int sums[256];
    int t = threadIdx.x;
    int base = blockIdx.x * SCAN_CHUNK + t * 4;
    int v0 = (base + 0 < N) ? cnt[base + 0] : 0;
    int v1 = (base + 1 < N) ? cnt[base + 1] : 0;
    int v2 = (base + 2 < N) ? cnt[base + 2] : 0;
    int v3 = (base + 3 < N) ? cnt[base + 3] : 0;
    sums[t] = v0 + v1 + v2 + v3;
    __syncthreads();
    for (int off = 1; off < 256; off <<= 1) {
        int x = sums[t];
        int y = (t >= off) ? sums[t - off] : 0;
        __syncthreads();
        sums[t] = x + y;
        __syncthreads();
    }
    int excl = (t > 0) ? sums[t - 1] : 0;
    if (base + 0 < N) rp[base + 0] = excl;  excl += v0;
    if (base + 1 < N) rp[base + 1] = excl;  excl += v1;
    if (base + 2 < N) rp[base + 2] = excl;  excl += v2;
    if (base + 3 < N) rp[base + 3] = excl;
    if (t == 255) bsum[blockIdx.x] = sums[255];
}

__global__ __launch_bounds__(128) void scan2(int* __restrict__ bsum, int B) {
    __shared__ int s[128];
    int t = threadIdx.x;
    s[t] = (t < B) ? bsum[t] : 0;
    __syncthreads();
    for (int off = 1; off < 128; off <<= 1) {
        int x = s[t];
        int y = (t >= off) ? s[t - off] : 0;
        __syncthreads();
        s[t] = x + y;
        __syncthreads();
    }
    if (t < B) bsum[t] = (t > 0) ? s[t - 1] : 0;
}

__global__ __launch_bounds__(256) void scan3(int* __restrict__ rp,
                                             int* __restrict__ cursor,
                                             const int* __restrict__ bsum,
                                             int N, int nE) {
    int i = blockIdx.x * 256 + threadIdx.x;
    if (i < N) {
        int v = rp[i] + bsum[i >> 10];
        rp[i] = v;
        cursor[i] = v;
    }
    if (i == 0) rp[N] = nE;
}

__global__ __launch_bounds__(256) void scatter_edges(const int* __restrict__ src,
                                                     const int* __restrict__ dst,
                                                     int* __restrict__ cursor,
                                                     int* __restrict__ ssrc, int nE) {
    int e = blockIdx.x * 256 + threadIdx.x;
    if (e < nE) {
        int pos = atomicAdd(&cursor[dst[e]], 1);
        ssrc[pos] = src[e];
    }
}

// ---------- projection: p = h @ W1a, weights in VGPRs, readlane broadcast ----------
__global__ __launch_bounds__(256, 3) void proj128(const float* __restrict__ h,
                                                  const float* __restrict__ W,
                                                  float* __restrict__ p, int M) {
    int lane = threadIdx.x & 63;
    float w[IN_DIM];
#pragma unroll
    for (int k = 0; k < IN_DIM; ++k) w[k] = W[k * HID + lane];  // column 'lane'
    int wave = (blockIdx.x * 256 + threadIdx.x) >> 6;
    int nW = gridDim.x * 4;
    for (int v = wave; v < M; v += nW) {
        float h0 = h[v * IN_DIM + lane];
        float h1 = h[v * IN_DIM + 64 + lane];
        float a0 = 0.f, a1 = 0.f, a2 = 0.f, a3 = 0.f;
#pragma unroll
        for (int k = 0; k < 64; k += 4) {
            a0 = fmaf(rl(h0, k + 0), w[k + 0], a0);
            a1 = fmaf(rl(h0, k + 1), w[k + 1], a1);
            a2 = fmaf(rl(h0, k + 2), w[k + 2], a2);
            a3 = fmaf(rl(h0, k + 3), w[k + 3], a3);
        }
#pragma unroll
        for (int k = 0; k < 64; k += 4) {
            a0 = fmaf(rl(h1, k + 0), w[64 + k + 0], a0);
            a1 = fmaf(rl(h1, k + 1), w[64 + k + 1], a1);
            a2 = fmaf(rl(h1, k + 2), w[64 + k + 2], a2);
            a3 = fmaf(rl(h1, k + 3), w[64 + k + 3], a3);
        }
        p[v * HID + lane] = (a0 + a1) + (a2 + a3);
    }
}

// ---------- fused layer: agg + relu + matvec1 + leaky (+ matvec2) ----------
// HAS_NEXT: out[v] = leaky(relu(p[v]+agg+ba) @ Wb + bb) @ Wn      (mid, -> p2)
// else:     out[v] = leaky(relu(p[v]+agg+ba) @ Wb + bb)           (final)
template<bool HAS_NEXT>
__global__ __launch_bounds__(256, 3) void fused_layer(const float* __restrict__ p,
                                                      const int* __restrict__ rp,
                                                      const int* __restrict__ ssrc,
                                                      const float* __restrict__ ba,
                                                      const float* __restrict__ Wb,
                                                      const float* __restrict__ bb,
                                                      const float* __restrict__ Wn,
                                                      float* __restrict__ out, int M) {
    int lane = threadIdx.x & 63;
    float wb[HID], wn[HID];
#pragma unroll
    for (int k = 0; k < HID; ++k) wb[k] = Wb[k * HID + lane];
    if (HAS_NEXT) {
#pragma unroll
        for (int k = 0; k < HID; ++k) wn[k] = Wn[k * HID + lane];
    }
    float vba = ba[lane], vbb = bb[lane];
    int wave = (blockIdx.x * 256 + threadIdx.x) >> 6;
    int nW = gridDim.x * 4;
    for (int v = wave; v < M; v += nW) {
        int beg = rp[v], end = rp[v + 1];
        float acc = p[v * HID + lane];   // self term
        int i = beg;
        for (; i + 4 <= end; i += 4) {
            int s0 = ssrc[i], s1 = ssrc[i + 1], s2 = ssrc[i + 2], s3 = ssrc[i + 3];
            float b0 = p[s0 * HID + lane];
            float b1 = p[s1 * HID + lane];
            float b2 = p[s2 * HID + lane];
            float b3 = p[s3 * HID + lane];
            acc += (b0 + b1) + (b2 + b3);
        }
        for (; i < end; ++i) acc += p[ssrc[i] * HID + lane];
        float t = fmaxf(acc + vba, 0.f);
        float a0 = 0.f, a1 = 0.f, a2 = 0.f, a3 = 0.f;
#pragma unroll
        for (int k = 0; k < HID; k += 4) {
            a0 = fmaf(rl(t, k + 0), wb[k + 0], a0);
            a1 = fmaf(rl(t, k + 1), wb[k + 1], a1);
            a2 = fmaf(rl(t, k + 2), wb[k + 2], a2);
            a3 = fmaf(rl(t, k + 3), wb[k + 3], a3);
        }
        float z = (a0 + a1) + (a2 + a3) + vbb;
        float h1 = (z > 0.f) ? z : z * NEG;
        if (HAS_NEXT) {
            a0 = a1 = a2 = a3 = 0.f;
#pragma unroll
            for (int k = 0; k < HID; k += 4) {
                a0 = fmaf(rl(h1, k + 0), wn[k + 0], a0);
                a1 = fmaf(rl(h1, k + 1), wn[k + 1], a1);
                a2 = fmaf(rl(h1, k + 2), wn[k + 2], a2);
                a3 = fmaf(rl(h1, k + 3), wn[k + 3], a3);
            }
            out[v * HID + lane] = (a0 + a1) + (a2 + a3);
        } else {
            out[v * HID + lane] = h1;
        }
    }
}

extern "C" void kernel_launch(void* const* d_in, const int* in_sizes, int n_in,
                              void* d_out, int out_size, void* d_ws, size_t ws_size,
                              hipStream_t stream) {
    const float* h   = (const float*)d_in[0];
    const int*   ei  = (const int*)d_in[1];
    const float* W1a = (const float*)d_in[2];
    const float* b1a = (const float*)d_in[3];
    const float* W1b = (const float*)d_in[4];
    const float* b1b = (const float*)d_in[5];
    const float* W2a = (const float*)d_in[6];
    const float* b2a = (const float*)d_in[7];
    const float* W2b = (const float*)d_in[8];
    const float* b2b = (const float*)d_in[9];

    int M  = in_sizes[0] / IN_DIM;  // 100000
    int nE = in_sizes[1] / 2;       // 1600000
    const int* src = ei;
    const int* dst = ei + nE;

    // workspace layout
    float* p1     = (float*)d_ws;                     // M*64 f32
    float* p2     = p1 + (size_t)M * HID;             // M*64 f32 (separate from d_out: layer-2 gathers read it)
    int*   rp     = (int*)(p2 + (size_t)M * HID);     // M+1
    int*   cursor = rp + (M + 1);                     // M
    int*   bsum   = cursor + M;                       // <=128
    int*   ssrc   = bsum + 128;                       // nE

    int nB    = (M + 255) / 256;
    int eB    = (nE + 255) / 256;
    int scanB = (M + SCAN_CHUNK - 1) / SCAN_CHUNK;    // 98
    int gB    = 2048;                                 // grid-stride blocks for dense kernels

    // layer-1 projection
    proj128<<<gB, 256, 0, stream>>>(h, W1a, p1, M);

    // CSR build (reused by both layers)
    zero_i32<<<nB, 256, 0, stream>>>(cursor, M);
    hist_dst<<<eB, 256, 0, stream>>>(dst, cursor, nE);
    scan1<<<scanB, 256, 0, stream>>>(cursor, rp, bsum, M);
    scan2<<<1, 128, 0, stream>>>(bsum, scanB);
    scan3<<<nB, 256, 0, stream>>>(rp, cursor, bsum, M, nE);
    scatter_edges<<<eB, 256, 0, stream>>>(src, dst, cursor, ssrc, nE);

    // layer 1: -> p2
    fused_layer<true><<<gB, 256, 0, stream>>>(p1, rp, ssrc, b1a, W1b, b1b, W2a, p2, M);
    // layer 2: -> out
    fused_layer<false><<<gB, 256, 0, stream>>>(p2, rp, ssrc, b2a, W2b, b2b, nullptr, (float*)d_out, M);
}

// Round 4
// 424.161 us; speedup vs baseline: 7.0458x; 1.1972x over previous
//
#include <hip/hip_runtime.h>

#define IN_DIM 128
#define HID 64
#define NEG 0.01f
#define SCAN_CHUNK 1024

typedef unsigned int uint;

__device__ __forceinline__ float rl(float v, int k) {
    return __int_as_float(__builtin_amdgcn_readlane(__float_as_int(v), k));
}
__device__ __forceinline__ float blo(uint u) { return __uint_as_float(u << 16); }
__device__ __forceinline__ float bhi(uint u) { return __uint_as_float(u & 0xffff0000u); }
// round-to-nearest-even f32->bf16 pair pack
__device__ __forceinline__ uint bfpair(float a, float b) {
    uint ua = __float_as_uint(a), ub = __float_as_uint(b);
    ua = (ua + 0x7fffu + ((ua >> 16) & 1u)) >> 16;
    ub = (ub + 0x7fffu + ((ub >> 16) & 1u)) & 0xffff0000u;
    return ua | ub;
}

// ---------- CSR build ----------

__global__ __launch_bounds__(256) void hist_dst(const int* __restrict__ dst,
                                                int* __restrict__ cnt, int nE) {
    int base = (blockIdx.x * 256 + threadIdx.x) * 4;
    if (base + 3 < nE) {
        int4 d = *(const int4*)(dst + base);
        atomicAdd(&cnt[d.x], 1);
        atomicAdd(&cnt[d.y], 1);
        atomicAdd(&cnt[d.z], 1);
        atomicAdd(&cnt[d.w], 1);
    } else {
        for (int e = base; e < nE; ++e) atomicAdd(&cnt[dst[e]], 1);
    }
}

__global__ __launch_bounds__(256) void scan1(const int* __restrict__ cnt,
                                             int* __restrict__ rp,
                                             int* __restrict__ bsum, int N) {
    __shared__ int sums[256];
    int t = threadIdx.x;
    int base = blockIdx.x * SCAN_CHUNK + t * 4;
    int v0 = (base + 0 < N) ? cnt[base + 0] : 0;
    int v1 = (base + 1 < N) ? cnt[base + 1] : 0;
    int v2 = (base + 2 < N) ? cnt[base + 2] : 0;
    int v3 = (base + 3 < N) ? cnt[base + 3] : 0;
    sums[t] = v0 + v1 + v2 + v3;
    __syncthreads();
    for (int off = 1; off < 256; off <<= 1) {
        int x = sums[t];
        int y = (t >= off) ? sums[t - off] : 0;
        __syncthreads();
        sums[t] = x + y;
        __syncthreads();
    }
    int excl = (t > 0) ? sums[t - 1] : 0;
    if (base + 0 < N) rp[base + 0] = excl;  excl += v0;
    if (base + 1 < N) rp[base + 1] = excl;  excl += v1;
    if (base + 2 < N) rp[base + 2] = excl;  excl += v2;
    if (base + 3 < N) rp[base + 3] = excl;
    if (t == 255) bsum[blockIdx.x] = sums[255];
}

__global__ __launch_bounds__(128) void scan2(int* __restrict__ bsum, int B) {
    __shared__ int s[128];
    int t = threadIdx.x;
    s[t] = (t < B) ? bsum[t] : 0;
    __syncthreads();
    for (int off = 1; off < 128; off <<= 1) {
        int x = s[t];
        int y = (t >= off) ? s[t - off] : 0;
        __syncthreads();
        s[t] = x + y;
        __syncthreads();
    }
    if (t < B) bsum[t] = (t > 0) ? s[t - 1] : 0;
}

__global__ __launch_bounds__(256) void scan3(int* __restrict__ rp,
                                             int* __restrict__ cursor,
                                             const int* __restrict__ bsum,
                                             int N, int nE) {
    int i = blockIdx.x * 256 + threadIdx.x;
    if (i < N) {
        int v = rp[i] + bsum[i >> 10];
        rp[i] = v;
        cursor[i] = v;
    }
    if (i == 0) rp[N] = nE;
}

__global__ __launch_bounds__(256) void scatter_edges(const int* __restrict__ src,
                                                     const int* __restrict__ dst,
                                                     int* __restrict__ cursor,
                                                     int* __restrict__ ssrc, int nE) {
    int base = (blockIdx.x * 256 + threadIdx.x) * 4;
    if (base + 3 < nE) {
        int4 d = *(const int4*)(dst + base);
        int4 s = *(const int4*)(src + base);
        int p0 = atomicAdd(&cursor[d.x], 1);
        int p1 = atomicAdd(&cursor[d.y], 1);
        int p2 = atomicAdd(&cursor[d.z], 1);
        int p3 = atomicAdd(&cursor[d.w], 1);
        ssrc[p0] = s.x; ssrc[p1] = s.y; ssrc[p2] = s.z; ssrc[p3] = s.w;
    } else {
        for (int e = base; e < nE; ++e) {
            int pos = atomicAdd(&cursor[dst[e]], 1);
            ssrc[pos] = src[e];
        }
    }
}

// ---------- projection: p1 = h @ W1a  -> bf16 packed ----------
__global__ __launch_bounds__(256, 3) void proj128(const float* __restrict__ h,
                                                  const float* __restrict__ W,
                                                  uint* __restrict__ pout, int M) {
    int lane = threadIdx.x & 63;
    float w[IN_DIM];
#pragma unroll
    for (int k = 0; k < IN_DIM; ++k) w[k] = W[k * HID + lane];
#pragma unroll
    for (int k = 0; k < IN_DIM; ++k) asm volatile("" : "+v"(w[k]));
    int wave = (blockIdx.x * 256 + threadIdx.x) >> 6;
    int nW = gridDim.x * 4;
    for (int v = wave; v < M; v += nW) {
        float h0 = h[(size_t)v * IN_DIM + lane];
        float h1 = h[(size_t)v * IN_DIM + 64 + lane];
        float a0 = 0.f, a1 = 0.f, a2 = 0.f, a3 = 0.f;
#pragma unroll
        for (int k = 0; k < 64; k += 4) {
            a0 = fmaf(rl(h0, k + 0), w[k + 0], a0);
            a1 = fmaf(rl(h0, k + 1), w[k + 1], a1);
            a2 = fmaf(rl(h0, k + 2), w[k + 2], a2);
            a3 = fmaf(rl(h0, k + 3), w[k + 3], a3);
        }
#pragma unroll
        for (int k = 0; k < 64; k += 4) {
            a0 = fmaf(rl(h1, k + 0), w[64 + k + 0], a0);
            a1 = fmaf(rl(h1, k + 1), w[64 + k + 1], a1);
            a2 = fmaf(rl(h1, k + 2), w[64 + k + 2], a2);
            a3 = fmaf(rl(h1, k + 3), w[64 + k + 3], a3);
        }
        float r = (a0 + a1) + (a2 + a3);
        float e0 = __shfl(r, (2 * lane) & 63);
        float e1 = __shfl(r, (2 * lane + 1) & 63);
        if (lane < 32) pout[(size_t)v * 32 + lane] = bfpair(e0, e1);
    }
}

// ---------- gather: z = relu(p[v] + sum_{src} p[src] + ba)  (bf16 in, bf16 out) ----------
__global__ __launch_bounds__(256, 8) void gather_z(const uint* __restrict__ pin,
                                                   const int* __restrict__ rp,
                                                   const int* __restrict__ ssrc,
                                                   const float* __restrict__ ba,
                                                   uint* __restrict__ zout, int M) {
    int lane = threadIdx.x & 63;
    int half = lane >> 5, col = lane & 31;
    int wave = (blockIdx.x * 256 + threadIdx.x) >> 6;
    int nW = gridDim.x * 4;
    for (int v = wave; v < M; v += nW) {
        int beg = rp[v], end = rp[v + 1];
        float f0 = 0.f, f1 = 0.f;
        for (int cb = beg; cb < end; cb += 64) {
            int n = min(64, end - cb);
            int eid = (lane < n) ? ssrc[cb + lane] : 0;
            int j = 0;
            for (; j + 8 <= n; j += 8) {
                int s0 = __shfl(eid, j + 0 + half);
                int s1 = __shfl(eid, j + 2 + half);
                int s2 = __shfl(eid, j + 4 + half);
                int s3 = __shfl(eid, j + 6 + half);
                uint u0 = pin[(size_t)s0 * 32 + col];
                uint u1 = pin[(size_t)s1 * 32 + col];
                uint u2 = pin[(size_t)s2 * 32 + col];
                uint u3 = pin[(size_t)s3 * 32 + col];
                f0 += blo(u0) + blo(u1);
                f1 += bhi(u0) + bhi(u1);
                f0 += blo(u2) + blo(u3);
                f1 += bhi(u2) + bhi(u3);
            }
            for (; j < n; j += 2) {
                int idx = j + half;
                int s = __shfl(eid, idx);
                uint u = 0;
                if (idx < n) u = pin[(size_t)s * 32 + col];
                f0 += blo(u);
                f1 += bhi(u);
            }
        }
        f0 += __shfl_xor(f0, 32);
        f1 += __shfl_xor(f1, 32);
        uint us = pin[(size_t)v * 32 + col];   // self term
        f0 += blo(us);
        f1 += bhi(us);
        float2 vb = ((const float2*)ba)[col];
        f0 = fmaxf(f0 + vb.x, 0.f);
        f1 = fmaxf(f1 + vb.y, 0.f);
        if (lane < 32) zout[(size_t)v * 32 + col] = bfpair(f0, f1);
    }
}

// ---------- matvec kernel: h1 = leaky(z@Wb + bb); [HAS_NEXT] p2 = h1@Wn (bf16) else out = h1 (f32) ----------
template<bool HAS_NEXT>
__global__ __launch_bounds__(256, 3) void mlp_gemm(const uint* __restrict__ zin,
                                                   const float* __restrict__ Wb,
                                                   const float* __restrict__ bb,
                                                   const float* __restrict__ Wn,
                                                   uint* __restrict__ pout,
                                                   float* __restrict__ fout, int M) {
    int lane = threadIdx.x & 63;
    float wb[HID];
#pragma unroll
    for (int k = 0; k < HID; ++k) wb[k] = Wb[k * HID + lane];
#pragma unroll
    for (int k = 0; k < HID; ++k) asm volatile("" : "+v"(wb[k]));
    float wn[HID];
    if (HAS_NEXT) {
#pragma unroll
        for (int k = 0; k < HID; ++k) wn[k] = Wn[k * HID + lane];
#pragma unroll
        for (int k = 0; k < HID; ++k) asm volatile("" : "+v"(wn[k]));
    }
    float vbb = bb[lane];
    int wave = (blockIdx.x * 256 + threadIdx.x) >> 6;
    int nW = gridDim.x * 4;
    for (int v = wave; v < M; v += nW) {
        uint u = zin[(size_t)v * 32 + (lane >> 1)];
        float t = (lane & 1) ? bhi(u) : blo(u);
        float a0 = 0.f, a1 = 0.f, a2 = 0.f, a3 = 0.f;
#pragma unroll
        for (int k = 0; k < HID; k += 4) {
            a0 = fmaf(rl(t, k + 0), wb[k + 0], a0);
            a1 = fmaf(rl(t, k + 1), wb[k + 1], a1);
            a2 = fmaf(rl(t, k + 2), wb[k + 2], a2);
            a3 = fmaf(rl(t, k + 3), wb[k + 3], a3);
        }
        float z = (a0 + a1) + (a2 + a3) + vbb;
        float h1 = (z > 0.f) ? z : z * NEG;
        if (HAS_NEXT) {
            a0 = a1 = a2 = a3 = 0.f;
#pragma unroll
            for (int k = 0; k < HID; k += 4) {
                a0 = fmaf(rl(h1, k + 0), wn[k + 0], a0);
                a1 = fmaf(rl(h1, k + 1), wn[k + 1], a1);
                a2 = fmaf(rl(h1, k + 2), wn[k + 2], a2);
                a3 = fmaf(rl(h1, k + 3), wn[k + 3], a3);
            }
            float r = (a0 + a1) + (a2 + a3);
            float e0 = __shfl(r, (2 * lane) & 63);
            float e1 = __shfl(r, (2 * lane + 1) & 63);
            if (lane < 32) pout[(size_t)v * 32 + lane] = bfpair(e0, e1);
        } else {
            fout[(size_t)v * HID + lane] = h1;
        }
    }
}

extern "C" void kernel_launch(void* const* d_in, const int* in_sizes, int n_in,
                              void* d_out, int out_size, void* d_ws, size_t ws_size,
                              hipStream_t stream) {
    const float* h   = (const float*)d_in[0];
    const int*   ei  = (const int*)d_in[1];
    const float* W1a = (const float*)d_in[2];
    const float* b1a = (const float*)d_in[3];
    const float* W1b = (const float*)d_in[4];
    const float* b1b = (const float*)d_in[5];
    const float* W2a = (const float*)d_in[6];
    const float* b2a = (const float*)d_in[7];
    const float* W2b = (const float*)d_in[8];
    const float* b2b = (const float*)d_in[9];

    int M  = in_sizes[0] / IN_DIM;  // 100000
    int nE = in_sizes[1] / 2;       // 1600000
    const int* src = ei;
    const int* dst = ei + nE;

    // workspace layout (bf16 features packed as uint: 2 channels per uint)
    uint*  p1     = (uint*)d_ws;                      // M*32 uints (12.8 MB)
    uint*  p2     = p1 + (size_t)M * 32;              // M*32
    uint*  z      = p2 + (size_t)M * 32;              // M*32 (shared by both layers)
    int*   rp     = (int*)(z + (size_t)M * 32);       // M+1
    int*   cursor = rp + (M + 1);                     // M
    int*   bsum   = cursor + M;                       // <=128
    int*   ssrc   = bsum + 128;                       // nE

    int nB    = (M + 255) / 256;
    int eB4   = (nE / 4 + 255) / 256;
    int scanB = (M + SCAN_CHUNK - 1) / SCAN_CHUNK;    // 98
    int gB    = 2048;

    // layer-1 projection (independent of CSR build)
    proj128<<<gB, 256, 0, stream>>>(h, W1a, p1, M);

    // CSR build (reused by both layers)
    hipMemsetAsync(cursor, 0, (size_t)M * sizeof(int), stream);
    hist_dst<<<eB4, 256, 0, stream>>>(dst, cursor, nE);
    scan1<<<scanB, 256, 0, stream>>>(cursor, rp, bsum, M);
    scan2<<<1, 128, 0, stream>>>(bsum, scanB);
    scan3<<<nB, 256, 0, stream>>>(rp, cursor, bsum, M, nE);
    scatter_edges<<<eB4, 256, 0, stream>>>(src, dst, cursor, ssrc, nE);

    // layer 1
    gather_z<<<gB, 256, 0, stream>>>(p1, rp, ssrc, b1a, z, M);
    mlp_gemm<true><<<gB, 256, 0, stream>>>(z, W1b, b1b, W2a, p2, nullptr, M);

    // layer 2
    gather_z<<<gB, 256, 0, stream>>>(p2, rp, ssrc, b2a, z, M);
    mlp_gemm<false><<<gB, 256, 0, stream>>>(z, W2b, b2b, nullptr, nullptr, (float*)d_out, M);
}

// Round 5
// 274.287 us; speedup vs baseline: 10.8957x; 1.5464x over previous
//
#include <hip/hip_runtime.h>

#define IN_DIM 128
#define HID 64
#define NEG 0.01f
#define NBUCK 512     // padded bucket count (real B = ceil(M/256) = 391)
#define EPT 16        // edges per thread per partition round (round = 4096 edges)

typedef unsigned int uint;

__device__ __forceinline__ float rl(float v, int k) {
    return __int_as_float(__builtin_amdgcn_readlane(__float_as_int(v), k));
}
__device__ __forceinline__ float blo(uint u) { return __uint_as_float(u << 16); }
__device__ __forceinline__ float bhi(uint u) { return __uint_as_float(u & 0xffff0000u); }
__device__ __forceinline__ uint bfpair(float a, float b) {
    uint ua = __float_as_uint(a), ub = __float_as_uint(b);
    ua = (ua + 0x7fffu + ((ua >> 16) & 1u)) >> 16;
    ub = (ub + 0x7fffu + ((ub >> 16) & 1u)) & 0xffff0000u;
    return ua | ub;
}

// ---------- CSR build, bucketed ----------

// LDS histogram of dst>>8 into B buckets, merged to global
__global__ __launch_bounds__(256) void coarse_hist(const int* __restrict__ dst,
                                                   int* __restrict__ gcnt, int nE, int B) {
    __shared__ int lc[NBUCK];
    for (int i = threadIdx.x; i < NBUCK; i += 256) lc[i] = 0;
    __syncthreads();
    int idx = blockIdx.x * 256 + threadIdx.x;
    int stride = gridDim.x * 256;
    for (int e = idx; e < nE; e += stride) atomicAdd(&lc[dst[e] >> 8], 1);
    __syncthreads();
    for (int i = threadIdx.x; i < B; i += 256) {
        int c = lc[i];
        if (c) atomicAdd(&gcnt[i], c);
    }
}

// one block: exclusive scan of gcnt[512] -> bbase, bcur
__global__ __launch_bounds__(256) void coarse_scan(const int* __restrict__ gcnt,
                                                   int* __restrict__ bbase,
                                                   int* __restrict__ bcur) {
    __shared__ int sc[NBUCK];
    int t = threadIdx.x;
    sc[t] = gcnt[t];
    sc[t + 256] = gcnt[t + 256];
    __syncthreads();
    for (int off = 1; off < NBUCK; off <<= 1) {
        int x0 = sc[t], x1 = sc[t + 256];
        int y0 = (t >= off) ? sc[t - off] : 0;
        int y1 = (t + 256 >= off) ? sc[t + 256 - off] : 0;
        __syncthreads();
        sc[t] = x0 + y0;
        sc[t + 256] = x1 + y1;
        __syncthreads();
    }
    int e0 = (t == 0) ? 0 : sc[t - 1];
    int e1 = sc[t + 255];
    bbase[t] = e0;        bcur[t] = e0;
    bbase[t + 256] = e1;  bcur[t + 256] = e1;
}

// round-based partition: edges -> per-bucket regions, packed src | (dstLow<<24)
__global__ __launch_bounds__(256) void partition(const int* __restrict__ src,
                                                 const int* __restrict__ dst,
                                                 int* __restrict__ bcur,
                                                 uint* __restrict__ ebuf,
                                                 int nE, int nRounds) {
    __shared__ int rcnt[NBUCK];
    __shared__ int chunk[NBUCK];
    int t = threadIdx.x;
    for (int r = blockIdx.x; r < nRounds; r += gridDim.x) {
        int base = r * (EPT * 256);
        for (int i = t; i < NBUCK; i += 256) rcnt[i] = 0;
        __syncthreads();
        uint pk[EPT];
        int rb[EPT];
#pragma unroll
        for (int j = 0; j < EPT; ++j) {
            int e = base + j * 256 + t;
            rb[j] = -1;
            if (e < nE) {
                int d = dst[e];
                int b = d >> 8;
                pk[j] = (uint)src[e] | ((uint)(d & 255) << 24);
                int rk = atomicAdd(&rcnt[b], 1);
                rb[j] = (rk << 9) | b;   // rk<=4095 (12b), b<=511 (9b)
            }
        }
        __syncthreads();
        for (int i = t; i < NBUCK; i += 256) {
            int c = rcnt[i];
            if (c) chunk[i] = atomicAdd(&bcur[i], c);
        }
        __syncthreads();
#pragma unroll
        for (int j = 0; j < EPT; ++j) {
            if (rb[j] >= 0) {
                int b = rb[j] & 511, rk = rb[j] >> 9;
                ebuf[chunk[b] + rk] = pk[j];
            }
        }
        __syncthreads();
    }
}

// one block per bucket: LDS hist+scan -> rp (coalesced), then dense scatter -> ssrc
__global__ __launch_bounds__(256) void bucket_csr(const uint* __restrict__ ebuf,
                                                  const int* __restrict__ bbase,
                                                  const int* __restrict__ bcur,
                                                  int* __restrict__ rp,
                                                  int* __restrict__ ssrc,
                                                  int M, int nE) {
    __shared__ int cnt[256], sc[256], cur[256];
    int b = blockIdx.x, t = threadIdx.x;
    int ebeg = bbase[b], eend = bcur[b];
    cnt[t] = 0;
    __syncthreads();
    for (int e = ebeg + t; e < eend; e += 256) atomicAdd(&cnt[ebuf[e] >> 24], 1);
    __syncthreads();
    sc[t] = cnt[t];
    __syncthreads();
    for (int off = 1; off < 256; off <<= 1) {
        int x = sc[t];
        int y = (t >= off) ? sc[t - off] : 0;
        __syncthreads();
        sc[t] = x + y;
        __syncthreads();
    }
    int excl = (t == 0) ? 0 : sc[t - 1];
    int node = (b << 8) + t;
    if (node < M) rp[node] = ebeg + excl;
    if (b == 0 && t == 0) rp[M] = nE;
    cur[t] = excl;
    __syncthreads();
    for (int e = ebeg + t; e < eend; e += 256) {
        uint u = ebuf[e];
        int r = atomicAdd(&cur[u >> 24], 1);
        ssrc[ebeg + r] = (int)(u & 0x00ffffffu);
    }
}

// ---------- projection: p1 = h @ W1a  -> bf16 packed ----------
__global__ __launch_bounds__(256, 3) void proj128(const float* __restrict__ h,
                                                  const float* __restrict__ W,
                                                  uint* __restrict__ pout, int M) {
    int lane = threadIdx.x & 63;
    float w[IN_DIM];
#pragma unroll
    for (int k = 0; k < IN_DIM; ++k) w[k] = W[k * HID + lane];
#pragma unroll
    for (int k = 0; k < IN_DIM; ++k) asm volatile("" : "+v"(w[k]));
    int wave = (blockIdx.x * 256 + threadIdx.x) >> 6;
    int nW = gridDim.x * 4;
    for (int v = wave; v < M; v += nW) {
        float h0 = h[(size_t)v * IN_DIM + lane];
        float h1 = h[(size_t)v * IN_DIM + 64 + lane];
        float a0 = 0.f, a1 = 0.f, a2 = 0.f, a3 = 0.f;
#pragma unroll
        for (int k = 0; k < 64; k += 4) {
            a0 = fmaf(rl(h0, k + 0), w[k + 0], a0);
            a1 = fmaf(rl(h0, k + 1), w[k + 1], a1);
            a2 = fmaf(rl(h0, k + 2), w[k + 2], a2);
            a3 = fmaf(rl(h0, k + 3), w[k + 3], a3);
        }
#pragma unroll
        for (int k = 0; k < 64; k += 4) {
            a0 = fmaf(rl(h1, k + 0), w[64 + k + 0], a0);
            a1 = fmaf(rl(h1, k + 1), w[64 + k + 1], a1);
            a2 = fmaf(rl(h1, k + 2), w[64 + k + 2], a2);
            a3 = fmaf(rl(h1, k + 3), w[64 + k + 3], a3);
        }
        float r = (a0 + a1) + (a2 + a3);
        float e0 = __shfl(r, (2 * lane) & 63);
        float e1 = __shfl(r, (2 * lane + 1) & 63);
        if (lane < 32) pout[(size_t)v * 32 + lane] = bfpair(e0, e1);
    }
}

// ---------- gather: z = relu(p[v] + sum_{src} p[src] + ba)  (bf16 in, bf16 out) ----------
__global__ __launch_bounds__(256, 8) void gather_z(const uint* __restrict__ pin,
                                                   const int* __restrict__ rp,
                                                   const int* __restrict__ ssrc,
                                                   const float* __restrict__ ba,
                                                   uint* __restrict__ zout, int M) {
    int lane = threadIdx.x & 63;
    int half = lane >> 5, col = lane & 31;
    int wave = (blockIdx.x * 256 + threadIdx.x) >> 6;
    int nW = gridDim.x * 4;
    for (int v = wave; v < M; v += nW) {
        int beg = rp[v], end = rp[v + 1];
        float f0 = 0.f, f1 = 0.f;
        for (int cb = beg; cb < end; cb += 64) {
            int n = min(64, end - cb);
            int eid = (lane < n) ? ssrc[cb + lane] : 0;
            int j = 0;
            for (; j + 8 <= n; j += 8) {
                int s0 = __shfl(eid, j + 0 + half);
                int s1 = __shfl(eid, j + 2 + half);
                int s2 = __shfl(eid, j + 4 + half);
                int s3 = __shfl(eid, j + 6 + half);
                uint u0 = pin[(size_t)s0 * 32 + col];
                uint u1 = pin[(size_t)s1 * 32 + col];
                uint u2 = pin[(size_t)s2 * 32 + col];
                uint u3 = pin[(size_t)s3 * 32 + col];
                f0 += blo(u0) + blo(u1);
                f1 += bhi(u0) + bhi(u1);
                f0 += blo(u2) + blo(u3);
                f1 += bhi(u2) + bhi(u3);
            }
            for (; j < n; j += 2) {
                int idx = j + half;
                int s = __shfl(eid, idx);
                uint u = 0;
                if (idx < n) u = pin[(size_t)s * 32 + col];
                f0 += blo(u);
                f1 += bhi(u);
            }
        }
        f0 += __shfl_xor(f0, 32);
        f1 += __shfl_xor(f1, 32);
        uint us = pin[(size_t)v * 32 + col];
        f0 += blo(us);
        f1 += bhi(us);
        float2 vb = ((const float2*)ba)[col];
        f0 = fmaxf(f0 + vb.x, 0.f);
        f1 = fmaxf(f1 + vb.y, 0.f);
        if (lane < 32) zout[(size_t)v * 32 + col] = bfpair(f0, f1);
    }
}

// ---------- matvec: h1 = leaky(z@Wb + bb); [HAS_NEXT] p2 = h1@Wn (bf16) else out = h1 (f32) ----------
template<bool HAS_NEXT>
__global__ __launch_bounds__(256, 3) void mlp_gemm(const uint* __restrict__ zin,
                                                   const float* __restrict__ Wb,
                                                   const float* __restrict__ bb,
                                                   const float* __restrict__ Wn,
                                                   uint* __restrict__ pout,
                                                   float* __restrict__ fout, int M) {
    int lane = threadIdx.x & 63;
    float wb[HID];
#pragma unroll
    for (int k = 0; k < HID; ++k) wb[k] = Wb[k * HID + lane];
#pragma unroll
    for (int k = 0; k < HID; ++k) asm volatile("" : "+v"(wb[k]));
    float wn[HID];
    if (HAS_NEXT) {
#pragma unroll
        for (int k = 0; k < HID; ++k) wn[k] = Wn[k * HID + lane];
#pragma unroll
        for (int k = 0; k < HID; ++k) asm volatile("" : "+v"(wn[k]));
    }
    float vbb = bb[lane];
    int wave = (blockIdx.x * 256 + threadIdx.x) >> 6;
    int nW = gridDim.x * 4;
    for (int v = wave; v < M; v += nW) {
        uint u = zin[(size_t)v * 32 + (lane >> 1)];
        float t = (lane & 1) ? bhi(u) : blo(u);
        float a0 = 0.f, a1 = 0.f, a2 = 0.f, a3 = 0.f;
#pragma unroll
        for (int k = 0; k < HID; k += 4) {
            a0 = fmaf(rl(t, k + 0), wb[k + 0], a0);
            a1 = fmaf(rl(t, k + 1), wb[k + 1], a1);
            a2 = fmaf(rl(t, k + 2), wb[k + 2], a2);
            a3 = fmaf(rl(t, k + 3), wb[k + 3], a3);
        }
        float z = (a0 + a1) + (a2 + a3) + vbb;
        float h1 = (z > 0.f) ? z : z * NEG;
        if (HAS_NEXT) {
            a0 = a1 = a2 = a3 = 0.f;
#pragma unroll
            for (int k = 0; k < HID; k += 4) {
                a0 = fmaf(rl(h1, k + 0), wn[k + 0], a0);
                a1 = fmaf(rl(h1, k + 1), wn[k + 1], a1);
                a2 = fmaf(rl(h1, k + 2), wn[k + 2], a2);
                a3 = fmaf(rl(h1, k + 3), wn[k + 3], a3);
            }
            float r = (a0 + a1) + (a2 + a3);
            float e0 = __shfl(r, (2 * lane) & 63);
            float e1 = __shfl(r, (2 * lane + 1) & 63);
            if (lane < 32) pout[(size_t)v * 32 + lane] = bfpair(e0, e1);
        } else {
            fout[(size_t)v * HID + lane] = h1;
        }
    }
}

extern "C" void kernel_launch(void* const* d_in, const int* in_sizes, int n_in,
                              void* d_out, int out_size, void* d_ws, size_t ws_size,
                              hipStream_t stream) {
    const float* h   = (const float*)d_in[0];
    const int*   ei  = (const int*)d_in[1];
    const float* W1a = (const float*)d_in[2];
    const float* b1a = (const float*)d_in[3];
    const float* W1b = (const float*)d_in[4];
    const float* b1b = (const float*)d_in[5];
    const float* W2a = (const float*)d_in[6];
    const float* b2a = (const float*)d_in[7];
    const float* W2b = (const float*)d_in[8];
    const float* b2b = (const float*)d_in[9];

    int M  = in_sizes[0] / IN_DIM;  // 100000
    int nE = in_sizes[1] / 2;       // 1600000
    const int* src = ei;
    const int* dst = ei + nE;

    int B = (M + 255) >> 8;         // 391 buckets of 256 nodes

    // workspace layout
    uint*  p1    = (uint*)d_ws;                     // M*32 uints (12.8 MB)
    uint*  p2    = p1 + (size_t)M * 32;             // M*32
    uint*  z     = p2 + (size_t)M * 32;             // M*32
    int*   gcnt  = (int*)(z + (size_t)M * 32);      // 512
    int*   bbase = gcnt + NBUCK;                    // 512
    int*   bcur  = bbase + NBUCK;                   // 512
    int*   rp    = bcur + NBUCK;                    // M+1
    int*   ssrc  = rp + (M + 1);                    // nE
    uint*  ebuf  = (uint*)(ssrc + nE);              // nE

    int gB = 2048;
    int nRounds = (nE + EPT * 256 - 1) / (EPT * 256);   // 391
    int gP = (nRounds + 1) / 2;                         // ~196, <=2 rounds/block

    // layer-1 projection (independent of CSR build)
    proj128<<<gB, 256, 0, stream>>>(h, W1a, p1, M);

    // CSR build (bucketed, reused by both layers)
    hipMemsetAsync(gcnt, 0, NBUCK * sizeof(int), stream);
    coarse_hist<<<256, 256, 0, stream>>>(dst, gcnt, nE, B);
    coarse_scan<<<1, 256, 0, stream>>>(gcnt, bbase, bcur);
    partition<<<gP, 256, 0, stream>>>(src, dst, bcur, ebuf, nE, nRounds);
    bucket_csr<<<B, 256, 0, stream>>>(ebuf, bbase, bcur, rp, ssrc, M, nE);

    // layer 1
    gather_z<<<gB, 256, 0, stream>>>(p1, rp, ssrc, b1a, z, M);
    mlp_gemm<true><<<gB, 256, 0, stream>>>(z, W1b, b1b, W2a, p2, nullptr, M);

    // layer 2
    gather_z<<<gB, 256, 0, stream>>>(p2, rp, ssrc, b2a, z, M);
    mlp_gemm<false><<<gB, 256, 0, stream>>>(z, W2b, b2b, nullptr, nullptr, (float*)d_out, M);
}

// Round 6
// 174.610 us; speedup vs baseline: 17.1156x; 1.5709x over previous
//
#include <hip/hip_runtime.h>

#define IN_DIM 128
#define HID 64
#define NEG 0.01f
#define NBUCK 512     // padded bucket count (real B = ceil(M/256) = 391)
#define EPT 16        // edges per thread per partition round

typedef unsigned int uint;
typedef unsigned short u16;
typedef __attribute__((ext_vector_type(8))) short s8v;   // 8 bf16 (4 VGPR)
typedef __attribute__((ext_vector_type(4))) float f4v;   // MFMA acc

__device__ __forceinline__ float blo(uint u) { return __uint_as_float(u << 16); }
__device__ __forceinline__ float bhi(uint u) { return __uint_as_float(u & 0xffff0000u); }
// RNE f32->bf16
__device__ __forceinline__ u16 bf16r(float x) {
    uint u = __float_as_uint(x);
    u = (u + 0x7fffu + ((u >> 16) & 1u)) >> 16;
    return (u16)u;
}
__device__ __forceinline__ uint bfpair(float a, float b) {
    uint ua = __float_as_uint(a), ub = __float_as_uint(b);
    ua = (ua + 0x7fffu + ((ua >> 16) & 1u)) >> 16;
    ub = (ub + 0x7fffu + ((ub >> 16) & 1u)) & 0xffff0000u;
    return ua | ub;
}
__device__ __forceinline__ s8v pack8(float4 x, float4 y) {
    uint4 qq = make_uint4(bfpair(x.x, x.y), bfpair(x.z, x.w),
                          bfpair(y.x, y.y), bfpair(y.z, y.w));
    return *reinterpret_cast<s8v*>(&qq);
}

// ---------- CSR build, bucketed (unchanged, proven) ----------

__global__ __launch_bounds__(256) void coarse_hist(const int* __restrict__ dst,
                                                   int* __restrict__ gcnt, int nE, int B) {
    __shared__ int lc[NBUCK];
    for (int i = threadIdx.x; i < NBUCK; i += 256) lc[i] = 0;
    __syncthreads();
    int idx = blockIdx.x * 256 + threadIdx.x;
    int stride = gridDim.x * 256;
    for (int e = idx; e < nE; e += stride) atomicAdd(&lc[dst[e] >> 8], 1);
    __syncthreads();
    for (int i = threadIdx.x; i < B; i += 256) {
        int c = lc[i];
        if (c) atomicAdd(&gcnt[i], c);
    }
}

__global__ __launch_bounds__(256) void coarse_scan(const int* __restrict__ gcnt,
                                                   int* __restrict__ bbase,
                                                   int* __restrict__ bcur) {
    __shared__ int sc[NBUCK];
    int t = threadIdx.x;
    sc[t] = gcnt[t];
    sc[t + 256] = gcnt[t + 256];
    __syncthreads();
    for (int off = 1; off < NBUCK; off <<= 1) {
        int x0 = sc[t], x1 = sc[t + 256];
        int y0 = (t >= off) ? sc[t - off] : 0;
        int y1 = (t + 256 >= off) ? sc[t + 256 - off] : 0;
        __syncthreads();
        sc[t] = x0 + y0;
        sc[t + 256] = x1 + y1;
        __syncthreads();
    }
    int e0 = (t == 0) ? 0 : sc[t - 1];
    int e1 = sc[t + 255];
    bbase[t] = e0;        bcur[t] = e0;
    bbase[t + 256] = e1;  bcur[t + 256] = e1;
}

__global__ __launch_bounds__(256) void partition(const int* __restrict__ src,
                                                 const int* __restrict__ dst,
                                                 int* __restrict__ bcur,
                                                 uint* __restrict__ ebuf,
                                                 int nE, int nRounds) {
    __shared__ int rcnt[NBUCK];
    __shared__ int chunk[NBUCK];
    int t = threadIdx.x;
    for (int r = blockIdx.x; r < nRounds; r += gridDim.x) {
        int base = r * (EPT * 256);
        for (int i = t; i < NBUCK; i += 256) rcnt[i] = 0;
        __syncthreads();
        uint pk[EPT];
        int rb[EPT];
#pragma unroll
        for (int j = 0; j < EPT; ++j) {
            int e = base + j * 256 + t;
            rb[j] = -1;
            if (e < nE) {
                int d = dst[e];
                int b = d >> 8;
                pk[j] = (uint)src[e] | ((uint)(d & 255) << 24);
                int rk = atomicAdd(&rcnt[b], 1);
                rb[j] = (rk << 9) | b;
            }
        }
        __syncthreads();
        for (int i = t; i < NBUCK; i += 256) {
            int c = rcnt[i];
            if (c) chunk[i] = atomicAdd(&bcur[i], c);
        }
        __syncthreads();
#pragma unroll
        for (int j = 0; j < EPT; ++j) {
            if (rb[j] >= 0) {
                int b = rb[j] & 511, rk = rb[j] >> 9;
                ebuf[chunk[b] + rk] = pk[j];
            }
        }
        __syncthreads();
    }
}

__global__ __launch_bounds__(256) void bucket_csr(const uint* __restrict__ ebuf,
                                                  const int* __restrict__ bbase,
                                                  const int* __restrict__ bcur,
                                                  int* __restrict__ rp,
                                                  int* __restrict__ ssrc,
                                                  int M, int nE) {
    __shared__ int cnt[256], sc[256], cur[256];
    int b = blockIdx.x, t = threadIdx.x;
    int ebeg = bbase[b], eend = bcur[b];
    cnt[t] = 0;
    __syncthreads();
    for (int e = ebeg + t; e < eend; e += 256) atomicAdd(&cnt[ebuf[e] >> 24], 1);
    __syncthreads();
    sc[t] = cnt[t];
    __syncthreads();
    for (int off = 1; off < 256; off <<= 1) {
        int x = sc[t];
        int y = (t >= off) ? sc[t - off] : 0;
        __syncthreads();
        sc[t] = x + y;
        __syncthreads();
    }
    int excl = (t == 0) ? 0 : sc[t - 1];
    int node = (b << 8) + t;
    if (node < M) rp[node] = ebeg + excl;
    if (b == 0 && t == 0) rp[M] = nE;
    cur[t] = excl;
    __syncthreads();
    for (int e = ebeg + t; e < eend; e += 256) {
        uint u = ebuf[e];
        int r = atomicAdd(&cur[u >> 24], 1);
        ssrc[ebeg + r] = (int)(u & 0x00ffffffu);
    }
}

// ---------- weight fragment prep: bf16 B-frags in lane-major order ----------
// layout: frag f, lane l, elem j -> wf[f*512 + l*8 + j]
// f = 0..15  : W1a (K=128): f = nt*4 + kt, kt<4
// f = 16..23 : W1b (K=64):  f-16 = nt*2 + kt, kt<2
// f = 24..31 : W2a
// f = 32..39 : W2b
__global__ __launch_bounds__(256) void prep_frags(const float* __restrict__ W1a,
                                                  const float* __restrict__ W1b,
                                                  const float* __restrict__ W2a,
                                                  const float* __restrict__ W2b,
                                                  u16* __restrict__ wf) {
    int t = threadIdx.x;
    for (int task = t; task < 40 * 64; task += 256) {
        int f = task >> 6, l = task & 63;
        const float* W;
        int kt, nt;
        if (f < 16)      { W = W1a; kt = f & 3;        nt = f >> 2; }
        else if (f < 24) { W = W1b; kt = (f - 16) & 1; nt = (f - 16) >> 1; }
        else if (f < 32) { W = W2a; kt = (f - 24) & 1; nt = (f - 24) >> 1; }
        else             { W = W2b; kt = (f - 32) & 1; nt = (f - 32) >> 1; }
        int col = nt * 16 + (l & 15);
        int k0  = kt * 32 + (l >> 4) * 8;
        for (int j = 0; j < 8; ++j)
            wf[f * 512 + l * 8 + j] = bf16r(W[(k0 + j) * HID + col]);
    }
}

// ---------- proj: p1 = h @ W1a via MFMA, bf16 out ----------
__global__ __launch_bounds__(256) void proj_mfma(const float* __restrict__ h,
                                                 const u16* __restrict__ wf,
                                                 u16* __restrict__ pout, int M) {
    int wid = threadIdx.x >> 6, lane = threadIdx.x & 63;
    int lr = lane & 15, kg = lane >> 4;
    int node0 = blockIdx.x * 64 + wid * 16;
    s8v bfr[16];
#pragma unroll
    for (int f = 0; f < 16; ++f)
        bfr[f] = *reinterpret_cast<const s8v*>(wf + f * 512 + lane * 8);
    f4v zero = {0.f, 0.f, 0.f, 0.f};
    f4v acc[4] = {zero, zero, zero, zero};
    int nodeA = min(node0 + lr, M - 1);
    const float* hp = h + (size_t)nodeA * IN_DIM + kg * 8;
#pragma unroll
    for (int kt = 0; kt < 4; ++kt) {
        float4 x = *reinterpret_cast<const float4*>(hp + kt * 32);
        float4 y = *reinterpret_cast<const float4*>(hp + kt * 32 + 4);
        s8v afr = pack8(x, y);
#pragma unroll
        for (int nt = 0; nt < 4; ++nt)
            acc[nt] = __builtin_amdgcn_mfma_f32_16x16x32_bf16(afr, bfr[nt * 4 + kt], acc[nt], 0, 0, 0);
    }
#pragma unroll
    for (int jj = 0; jj < 4; ++jj) {
        int node = node0 + kg * 4 + jj;   // D row = (lane>>4)*4 + reg
        if (node < M) {
#pragma unroll
            for (int nt = 0; nt < 4; ++nt)
                pout[(size_t)node * HID + nt * 16 + lr] = bf16r(acc[nt][jj]);
        }
    }
}

// ---------- gather: z = relu(p[v] + sum p[src] + ba)  (bf16 in/out; unchanged) ----------
__global__ __launch_bounds__(256, 8) void gather_z(const uint* __restrict__ pin,
                                                   const int* __restrict__ rp,
                                                   const int* __restrict__ ssrc,
                                                   const float* __restrict__ ba,
                                                   uint* __restrict__ zout, int M) {
    int lane = threadIdx.x & 63;
    int half = lane >> 5, col = lane & 31;
    int wave = (blockIdx.x * 256 + threadIdx.x) >> 6;
    int nW = gridDim.x * 4;
    for (int v = wave; v < M; v += nW) {
        int beg = rp[v], end = rp[v + 1];
        float f0 = 0.f, f1 = 0.f;
        for (int cb = beg; cb < end; cb += 64) {
            int n = min(64, end - cb);
            int eid = (lane < n) ? ssrc[cb + lane] : 0;
            int j = 0;
            for (; j + 8 <= n; j += 8) {
                int s0 = __shfl(eid, j + 0 + half);
                int s1 = __shfl(eid, j + 2 + half);
                int s2 = __shfl(eid, j + 4 + half);
                int s3 = __shfl(eid, j + 6 + half);
                uint u0 = pin[(size_t)s0 * 32 + col];
                uint u1 = pin[(size_t)s1 * 32 + col];
                uint u2 = pin[(size_t)s2 * 32 + col];
                uint u3 = pin[(size_t)s3 * 32 + col];
                f0 += blo(u0) + blo(u1);
                f1 += bhi(u0) + bhi(u1);
                f0 += blo(u2) + blo(u3);
                f1 += bhi(u2) + bhi(u3);
            }
            for (; j < n; j += 2) {
                int idx = j + half;
                int s = __shfl(eid, idx);
                uint u = 0;
                if (idx < n) u = pin[(size_t)s * 32 + col];
                f0 += blo(u);
                f1 += bhi(u);
            }
        }
        f0 += __shfl_xor(f0, 32);
        f1 += __shfl_xor(f1, 32);
        uint us = pin[(size_t)v * 32 + col];
        f0 += blo(us);
        f1 += bhi(us);
        float2 vb = ((const float2*)ba)[col];
        f0 = fmaxf(f0 + vb.x, 0.f);
        f1 = fmaxf(f1 + vb.y, 0.f);
        if (lane < 32) zout[(size_t)v * 32 + col] = bfpair(f0, f1);
    }
}

// ---------- MLP via MFMA: h1 = leaky(z@Wb + bb); [HAS_NEXT] p2 = h1@Wn ----------
template<bool HAS_NEXT>
__global__ __launch_bounds__(256) void mlp_mfma(const u16* __restrict__ zin,
                                                const u16* __restrict__ wfb,
                                                const float* __restrict__ bb,
                                                const u16* __restrict__ wfn,
                                                u16* __restrict__ pout,
                                                float* __restrict__ fout, int M) {
    int wid = threadIdx.x >> 6, lane = threadIdx.x & 63;
    int lr = lane & 15, kg = lane >> 4;
    int node0 = blockIdx.x * 64 + wid * 16;
    s8v bfr[8];
#pragma unroll
    for (int f = 0; f < 8; ++f)
        bfr[f] = *reinterpret_cast<const s8v*>(wfb + f * 512 + lane * 8);
    f4v zero = {0.f, 0.f, 0.f, 0.f};
    f4v acc[4] = {zero, zero, zero, zero};
    int nodeA = min(node0 + lr, M - 1);
    const u16* zp = zin + (size_t)nodeA * HID + kg * 8;
#pragma unroll
    for (int kt = 0; kt < 2; ++kt) {
        s8v afr = *reinterpret_cast<const s8v*>(zp + kt * 32);
#pragma unroll
        for (int nt = 0; nt < 4; ++nt)
            acc[nt] = __builtin_amdgcn_mfma_f32_16x16x32_bf16(afr, bfr[nt * 2 + kt], acc[nt], 0, 0, 0);
    }
    float h1[4][4];
#pragma unroll
    for (int nt = 0; nt < 4; ++nt) {
        float b = bb[nt * 16 + lr];
#pragma unroll
        for (int jj = 0; jj < 4; ++jj) {
            float v = acc[nt][jj] + b;
            h1[nt][jj] = (v > 0.f) ? v : v * NEG;
        }
    }
    if constexpr (!HAS_NEXT) {
#pragma unroll
        for (int jj = 0; jj < 4; ++jj) {
            int node = node0 + kg * 4 + jj;
            if (node < M) {
#pragma unroll
                for (int nt = 0; nt < 4; ++nt)
                    fout[(size_t)node * HID + nt * 16 + lr] = h1[nt][jj];
            }
        }
    } else {
        // per-wave LDS transpose: D layout -> A layout (stride 68 => 2-way bank aliasing = free)
        __shared__ float tls[4][16][68];
#pragma unroll
        for (int nt = 0; nt < 4; ++nt)
#pragma unroll
            for (int jj = 0; jj < 4; ++jj)
                tls[wid][kg * 4 + jj][nt * 16 + lr] = h1[nt][jj];
        s8v wfr[8];
#pragma unroll
        for (int f = 0; f < 8; ++f)
            wfr[f] = *reinterpret_cast<const s8v*>(wfn + f * 512 + lane * 8);
        f4v acc2[4] = {zero, zero, zero, zero};
#pragma unroll
        for (int kt = 0; kt < 2; ++kt) {
            float4 x = *reinterpret_cast<const float4*>(&tls[wid][lr][kt * 32 + kg * 8]);
            float4 y = *reinterpret_cast<const float4*>(&tls[wid][lr][kt * 32 + kg * 8 + 4]);
            s8v afr = pack8(x, y);
#pragma unroll
            for (int nt = 0; nt < 4; ++nt)
                acc2[nt] = __builtin_amdgcn_mfma_f32_16x16x32_bf16(afr, wfr[nt * 2 + kt], acc2[nt], 0, 0, 0);
        }
#pragma unroll
        for (int jj = 0; jj < 4; ++jj) {
            int node = node0 + kg * 4 + jj;
            if (node < M) {
#pragma unroll
                for (int nt = 0; nt < 4; ++nt)
                    pout[(size_t)node * HID + nt * 16 + lr] = bf16r(acc2[nt][jj]);
            }
        }
    }
}

extern "C" void kernel_launch(void* const* d_in, const int* in_sizes, int n_in,
                              void* d_out, int out_size, void* d_ws, size_t ws_size,
                              hipStream_t stream) {
    const float* h   = (const float*)d_in[0];
    const int*   ei  = (const int*)d_in[1];
    const float* W1a = (const float*)d_in[2];
    const float* b1a = (const float*)d_in[3];
    const float* W1b = (const float*)d_in[4];
    const float* b1b = (const float*)d_in[5];
    const float* W2a = (const float*)d_in[6];
    const float* b2a = (const float*)d_in[7];
    const float* W2b = (const float*)d_in[8];
    const float* b2b = (const float*)d_in[9];

    int M  = in_sizes[0] / IN_DIM;  // 100000
    int nE = in_sizes[1] / 2;       // 1600000
    const int* src = ei;
    const int* dst = ei + nE;

    int B = (M + 255) >> 8;         // 391 buckets

    // workspace layout
    uint*  p1    = (uint*)d_ws;                     // M*32 uints (bf16 pairs)
    uint*  p2    = p1 + (size_t)M * 32;
    uint*  z     = p2 + (size_t)M * 32;
    int*   gcnt  = (int*)(z + (size_t)M * 32);      // 512
    int*   bbase = gcnt + NBUCK;
    int*   bcur  = bbase + NBUCK;
    int*   rp    = bcur + NBUCK;                    // M+1
    int*   ssrc  = rp + (M + 1);                    // nE
    uint*  ebuf  = (uint*)(ssrc + nE);              // nE
    u16*   wf    = (u16*)(ebuf + nE);               // 40*512 u16 = 40 KB

    int gB = 2048;
    int mB = (M + 63) / 64;                             // 1563
    int nRounds = (nE + EPT * 256 - 1) / (EPT * 256);   // 391
    int gP = (nRounds + 1) / 2;

    // weight frag prep, then layer-1 projection
    prep_frags<<<1, 256, 0, stream>>>(W1a, W1b, W2a, W2b, wf);
    proj_mfma<<<mB, 256, 0, stream>>>(h, wf, (u16*)p1, M);

    // CSR build (bucketed, reused by both layers)
    hipMemsetAsync(gcnt, 0, NBUCK * sizeof(int), stream);
    coarse_hist<<<256, 256, 0, stream>>>(dst, gcnt, nE, B);
    coarse_scan<<<1, 256, 0, stream>>>(gcnt, bbase, bcur);
    partition<<<gP, 256, 0, stream>>>(src, dst, bcur, ebuf, nE, nRounds);
    bucket_csr<<<B, 256, 0, stream>>>(ebuf, bbase, bcur, rp, ssrc, M, nE);

    // layer 1
    gather_z<<<gB, 256, 0, stream>>>(p1, rp, ssrc, b1a, z, M);
    mlp_mfma<true><<<mB, 256, 0, stream>>>((const u16*)z, wf + 16 * 512, b1b, wf + 24 * 512,
                                           (u16*)p2, nullptr, M);
    // layer 2
    gather_z<<<gB, 256, 0, stream>>>(p2, rp, ssrc, b2a, z, M);
    mlp_mfma<false><<<mB, 256, 0, stream>>>((const u16*)z, wf + 32 * 512, b2b, nullptr,
                                            nullptr, (float*)d_out, M);
}